// Round 8
// baseline (70.437 us; speedup 1.0000x reference)
//
#include <hip/hip_runtime.h>
#include <math.h>

// HPSS fused, fp16 LDS, 64x64 tiles, one-round grid. S (2,1,1025,2048) fp32.
// harm = median_31 along T (zero pad), perc = median_31 along F.
// outH = S*h^2/(h^2+p^2), outP = S*p^2/(h^2+p^2)   (softmask Z cancels).
//
// Round-7 lesson: 2112 blocks vs capacity 2048 -> a 64-block tail costs a
// full extra cohort round; identical timing at 5 vs 8 blocks/CU proved the
// kernel is cohort-round-bound, not occupancy-bound. This version:
//   - 64(f) x 64(t) tiles -> grid 32x17x2 = 1088 <= capacity (26.9KB LDS ->
//     6 blocks/CU = 1536): ONE cohort, no tail round.
//   - RW=16 in BOTH phases (Batcher-32 init amortized /16, was /8).
//   - fp16 window math (monotone rounding => median commutes with fp16 cast);
//     exact fp32 S multiplier prefetched 16-deep in phase P.
// Slide = delete+insert at O(1) dependency depth:
//   D[i] = (w[i] < x_old) ? w[i] : w[i+1]; w'[i] = med3(D[i-1], x_new, D[i]).

#define DIM_T 2048
#define DIM_F 1025
#define HALF 15
#define FT 64            // output f-rows per tile
#define TT 64            // output t-cols per tile
#define RW 16            // outputs per thread along the sliding axis
#define TROWS (FT + 30)  // 94 staged rows
#define TCOLS (TT + 30)  // 94 staged cols
#define TSTR 98          // halves; 49 dwords (odd) -> conflict-free strided
#define HSTR 66          // halves; 33 dwords (odd)

typedef _Float16 h16;

__device__ __forceinline__ h16 hmin(h16 a, h16 b) { return a < b ? a : b; }
__device__ __forceinline__ h16 hmax(h16 a, h16 b) { return a > b ? a : b; }
__device__ __forceinline__ h16 hmed3(h16 a, h16 b, h16 c) {
#if __has_builtin(__builtin_amdgcn_fmed3h)
    return __builtin_amdgcn_fmed3h(a, b, c);
#else
    return hmax(hmin(a, b), hmin(hmax(a, b), c));
#endif
}

__device__ __forceinline__ void ce(h16& a, h16& b) {
    const h16 mn = hmin(a, b);
    b = hmax(a, b);
    a = mn;
}

__device__ __forceinline__ void sort32(h16 (&a)[32]) {
#pragma unroll
    for (int p = 1; p < 32; p <<= 1) {
#pragma unroll
        for (int k = p; k >= 1; k >>= 1) {
#pragma unroll
            for (int j = k & (p - 1); j + k < 32; j += 2 * k) {
#pragma unroll
                for (int i = 0; i < k; ++i) {
                    if (i + j + k < 32) {
                        if ((i + j) / (2 * p) == (i + j + k) / (2 * p)) {
                            ce(a[i + j], a[i + j + k]);
                        }
                    }
                }
            }
        }
    }
}

// sorted-window slide: remove x_old (present in w[0..30]), insert x_new.
// w[31] must be +INF and is preserved. 31 indep (cmp+sel) + 31 indep med3.
__device__ __forceinline__ void slide(h16 (&w)[32], h16 x_old, h16 x_new) {
    h16 dprev = (w[0] < x_old) ? w[0] : w[1];
    h16 rprev = hmin(x_new, dprev);
#pragma unroll
    for (int i = 1; i < 31; ++i) {
        const h16 di = (w[i] < x_old) ? w[i] : w[i + 1];
        const h16 ri = hmed3(dprev, x_new, di);
        w[i - 1] = rprev;
        dprev = di;
        rprev = ri;
    }
    w[30] = rprev;
}

__global__ __launch_bounds__(256, 6) void hpss_fused(const float* __restrict__ S,
                                                     float* __restrict__ outH,
                                                     float* __restrict__ outP) {
    __shared__ h16 tile[TROWS * TSTR];  // 18424 B
    __shared__ h16 hl[FT * HSTR];       //  8448 B

    const int tid = threadIdx.x;
    const int t0  = blockIdx.x * TT;
    const int f0  = blockIdx.y * FT;
    const int b   = blockIdx.z;
    const float* __restrict__ Sb = S + (size_t)b * DIM_F * DIM_T;

    // ---- stage 94x94 tile as fp16, coalesced (consecutive tid -> t) ----
    const bool interior = (blockIdx.x != 0) & (blockIdx.x != gridDim.x - 1) &
                          (f0 >= HALF) & (f0 + FT + HALF <= DIM_F);
    if (interior) {
#pragma unroll
        for (int it = 0; it < (TROWS * TCOLS + 255) / 256; ++it) {  // 35 iters
            const int li = it * 256 + tid;
            if (li < TROWS * TCOLS) {
                const int row = li / TCOLS;
                const int pos = li - row * TCOLS;
                tile[row * TSTR + pos] =
                    (h16)Sb[(size_t)(f0 - HALF + row) * DIM_T + (t0 - HALF + pos)];
            }
        }
    } else {
#pragma unroll
        for (int it = 0; it < (TROWS * TCOLS + 255) / 256; ++it) {
            const int li = it * 256 + tid;
            if (li < TROWS * TCOLS) {
                const int row = li / TCOLS;
                const int pos = li - row * TCOLS;
                const int f = f0 - HALF + row;
                const int t = t0 - HALF + pos;
                float v = 0.0f;
                if ((unsigned)f < (unsigned)DIM_F && (unsigned)t < (unsigned)DIM_T)
                    v = Sb[(size_t)f * DIM_T + t];
                tile[row * TSTR + pos] = (h16)v;
            }
        }
    }
    __syncthreads();

    // ---- phase H: harmonic medians (slide along t) -> hl[f][t] ----
    {
        const int fl = tid & 63;          // output f row 0..63
        const int tb = (tid >> 6) * RW;   // t chunk base 0,16,32,48
        const h16* lr = tile + (fl + HALF) * TSTR;  // input row f0+fl

        h16 w[32];
        w[31] = (h16)INFINITY;
#pragma unroll
        for (int d = 0; d < 31; ++d) w[d] = lr[tb + d];
        sort32(w);
#pragma unroll
        for (int s = 0; s < RW; ++s) {
            hl[fl * HSTR + tb + s] = w[15];
            if (s < RW - 1) slide(w, lr[tb + s], lr[tb + s + 31]);
        }
    }
    __syncthreads();

    // ---- phase P: percussive medians (slide along f) + combine + store ----
    {
        const int lane = tid & 63;        // t within tile
        const int fb   = (tid >> 6) * RW; // f chunk base 0,16,32,48
        const int t    = t0 + lane;

        // prefetch exact fp32 S values (consumed one per slide step)
        float sv[RW];
#pragma unroll
        for (int s = 0; s < RW; ++s) {
            const int f = f0 + fb + s;
            sv[s] = (f < DIM_F) ? Sb[(size_t)f * DIM_T + t] : 0.0f;
        }

        h16 w[32];
        w[31] = (h16)INFINITY;
#pragma unroll
        for (int d = 0; d < 31; ++d) w[d] = tile[(fb + d) * TSTR + HALF + lane];
        sort32(w);
#pragma unroll
        for (int s = 0; s < RW; ++s) {
            const int f = f0 + fb + s;
            if (f < DIM_F) {
                const float perc = (float)w[15];
                const float harm = (float)hl[(fb + s) * HSTR + lane];
                const float h2 = harm * harm;
                const float p2 = perc * perc;
                const float inv = __builtin_amdgcn_rcpf(h2 + p2);  // 0 -> INF; 0*INF=NaN matches ref 0/0
                const size_t oi = ((size_t)b * DIM_F + f) * DIM_T + t;
                outH[oi] = sv[s] * h2 * inv;
                outP[oi] = sv[s] * p2 * inv;
            }
            if (s < RW - 1)
                slide(w, tile[(fb + s) * TSTR + HALF + lane],
                         tile[(fb + s + 31) * TSTR + HALF + lane]);
        }
    }
}

extern "C" void kernel_launch(void* const* d_in, const int* in_sizes, int n_in,
                              void* d_out, int out_size, void* d_ws, size_t ws_size,
                              hipStream_t stream) {
    const float* S = (const float*)d_in[0];
    float* outH = (float*)d_out;
    float* outP = outH + (size_t)2 * DIM_F * DIM_T;

    dim3 grid(DIM_T / TT, (DIM_F + FT - 1) / FT, 2);  // 32 x 17 x 2 = 1088
    hpss_fused<<<grid, 256, 0, stream>>>(S, outH, outP);
}

// Round 9
// 50.098 us; speedup vs baseline: 1.4060x; 1.4060x over previous
//
#include <hip/hip_runtime.h>
#include <math.h>

// HPSS fused, fp16 LDS, 32(f) x 128(t) tiles, one-round grid.
// S (2,1,1025,2048) fp32. harm = median_31 along T (zero pad), perc = along F.
// outH = S*h^2/(h^2+p^2), outP = S*p^2/(h^2+p^2)   (softmask Z cancels).
//
// Round-8 lesson: sv[16] register array + 32-wide window => spill-everything
// regalloc fallback (WRITE_SIZE 102MB vs 33MB outputs). This version keeps NO
// long-lived register arrays besides the window itself.
//   - 32x128 tile -> RW=16 in BOTH phases (sort amortized /16), grid
//     16x33x2 = 1056 blocks <= 1280 resident capacity (27.9KB LDS -> 5
//     blocks/CU): single cohort, no tail round.
//   - fp16 window math (monotone rounding => median commutes with the cast).
//     sv ALSO from fp16 tile: adds <=2^-11*S abs error; absmax has sat at
//     0.0039 (threshold 2e-2) for 8 rounds -> safe. Zero global re-reads.
//   - LDS strides odd in dwords: TSTR=158 halves (79 dw), HSTR=130 (65 dw)
//     -> conflict-free for row-strided (phase H) and contiguous (phase P).
// Slide = delete+insert at O(1) dependency depth:
//   D[i] = (w[i] < x_old) ? w[i] : w[i+1]; w'[i] = med3(D[i-1], x_new, D[i]).

#define DIM_T 2048
#define DIM_F 1025
#define HALF 15
#define FT 32             // output f-rows per tile
#define TT 128            // output t-cols per tile
#define RW 16             // outputs per thread along the sliding axis
#define TROWS (FT + 30)   // 62 staged rows
#define TCOLS (TT + 30)   // 158 staged cols
#define TSTR 158          // halves; 79 dwords (odd) -> conflict-free
#define HSTR 130          // halves; 65 dwords (odd)

typedef _Float16 h16;

__device__ __forceinline__ h16 hmin(h16 a, h16 b) { return a < b ? a : b; }
__device__ __forceinline__ h16 hmax(h16 a, h16 b) { return a > b ? a : b; }
__device__ __forceinline__ h16 hmed3(h16 a, h16 b, h16 c) {
#if __has_builtin(__builtin_amdgcn_fmed3h)
    return __builtin_amdgcn_fmed3h(a, b, c);
#else
    return hmax(hmin(a, b), hmin(hmax(a, b), c));
#endif
}

__device__ __forceinline__ void ce(h16& a, h16& b) {
    const h16 mn = hmin(a, b);
    b = hmax(a, b);
    a = mn;
}

__device__ __forceinline__ void sort32(h16 (&a)[32]) {
#pragma unroll
    for (int p = 1; p < 32; p <<= 1) {
#pragma unroll
        for (int k = p; k >= 1; k >>= 1) {
#pragma unroll
            for (int j = k & (p - 1); j + k < 32; j += 2 * k) {
#pragma unroll
                for (int i = 0; i < k; ++i) {
                    if (i + j + k < 32) {
                        if ((i + j) / (2 * p) == (i + j + k) / (2 * p)) {
                            ce(a[i + j], a[i + j + k]);
                        }
                    }
                }
            }
        }
    }
}

// sorted-window slide: remove x_old (present in w[0..30]), insert x_new.
// w[31] must be +INF and is preserved. 31 indep (cmp+sel) + 31 indep med3.
__device__ __forceinline__ void slide(h16 (&w)[32], h16 x_old, h16 x_new) {
    h16 dprev = (w[0] < x_old) ? w[0] : w[1];
    h16 rprev = hmin(x_new, dprev);
#pragma unroll
    for (int i = 1; i < 31; ++i) {
        const h16 di = (w[i] < x_old) ? w[i] : w[i + 1];
        const h16 ri = hmed3(dprev, x_new, di);
        w[i - 1] = rprev;
        dprev = di;
        rprev = ri;
    }
    w[30] = rprev;
}

__global__ __launch_bounds__(256, 4) void hpss_fused(const float* __restrict__ S,
                                                     float* __restrict__ outH,
                                                     float* __restrict__ outP) {
    __shared__ h16 tile[TROWS * TSTR];  // 19592 B
    __shared__ h16 hl[FT * HSTR];       //  8320 B

    const int tid = threadIdx.x;
    const int t0  = blockIdx.x * TT;
    const int f0  = blockIdx.y * FT;
    const int b   = blockIdx.z;
    const float* __restrict__ Sb = S + (size_t)b * DIM_F * DIM_T;

    // ---- stage 62x158 tile as fp16, coalesced (consecutive tid -> t) ----
    const bool interior = (blockIdx.x != 0) & (blockIdx.x != gridDim.x - 1) &
                          (f0 >= HALF) & (f0 + FT + HALF <= DIM_F);
    if (interior) {
#pragma unroll
        for (int it = 0; it < (TROWS * TCOLS + 255) / 256; ++it) {  // 39 iters
            const int li = it * 256 + tid;
            if (li < TROWS * TCOLS) {
                const int row = li / TCOLS;
                const int pos = li - row * TCOLS;
                tile[row * TSTR + pos] =
                    (h16)Sb[(size_t)(f0 - HALF + row) * DIM_T + (t0 - HALF + pos)];
            }
        }
    } else {
#pragma unroll
        for (int it = 0; it < (TROWS * TCOLS + 255) / 256; ++it) {
            const int li = it * 256 + tid;
            if (li < TROWS * TCOLS) {
                const int row = li / TCOLS;
                const int pos = li - row * TCOLS;
                const int f = f0 - HALF + row;
                const int t = t0 - HALF + pos;
                float v = 0.0f;
                if ((unsigned)f < (unsigned)DIM_F && (unsigned)t < (unsigned)DIM_T)
                    v = Sb[(size_t)f * DIM_T + t];
                tile[row * TSTR + pos] = (h16)v;
            }
        }
    }
    __syncthreads();

    // ---- phase H: harmonic medians (slide along t) -> hl[f][t] ----
    {
        const int fl = tid & 31;          // output f row 0..31
        const int tb = (tid >> 5) * RW;   // t chunk base 0..112
        const h16* lr = tile + (fl + HALF) * TSTR;  // input row f0+fl

        h16 w[32];
        w[31] = (h16)INFINITY;
#pragma unroll
        for (int d = 0; d < 31; ++d) w[d] = lr[tb + d];
        sort32(w);
#pragma unroll
        for (int s = 0; s < RW; ++s) {
            hl[fl * HSTR + tb + s] = w[15];
            if (s < RW - 1) slide(w, lr[tb + s], lr[tb + s + 31]);
        }
    }
    __syncthreads();

    // ---- phase P: percussive medians (slide along f) + combine + store ----
    {
        const int lane = tid & 127;        // t within tile 0..127
        const int fb   = (tid >> 7) * RW;  // f chunk base 0 or 16
        const int t    = t0 + lane;

        h16 w[32];
        w[31] = (h16)INFINITY;
#pragma unroll
        for (int d = 0; d < 31; ++d) w[d] = tile[(fb + d) * TSTR + HALF + lane];
        sort32(w);
#pragma unroll
        for (int s = 0; s < RW; ++s) {
            const int f = f0 + fb + s;
            if (f < DIM_F) {
                const float perc = (float)w[15];
                const float harm = (float)hl[(fb + s) * HSTR + lane];
                const float sv   = (float)tile[(fb + s + HALF) * TSTR + HALF + lane];
                const float h2 = harm * harm;
                const float p2 = perc * perc;
                const float inv = __builtin_amdgcn_rcpf(h2 + p2);  // 0 -> INF; (sv*0)*INF=NaN matches ref 0/0
                const size_t oi = ((size_t)b * DIM_F + f) * DIM_T + t;
                outH[oi] = sv * h2 * inv;
                outP[oi] = sv * p2 * inv;
            }
            if (s < RW - 1)
                slide(w, tile[(fb + s) * TSTR + HALF + lane],
                         tile[(fb + s + 31) * TSTR + HALF + lane]);
        }
    }
}

extern "C" void kernel_launch(void* const* d_in, const int* in_sizes, int n_in,
                              void* d_out, int out_size, void* d_ws, size_t ws_size,
                              hipStream_t stream) {
    const float* S = (const float*)d_in[0];
    float* outH = (float*)d_out;
    float* outP = outH + (size_t)2 * DIM_F * DIM_T;

    dim3 grid(DIM_T / TT, (DIM_F + FT - 1) / FT, 2);  // 16 x 33 x 2 = 1056
    hpss_fused<<<grid, 256, 0, stream>>>(S, outH, outP);
}

// Round 10
// 43.718 us; speedup vs baseline: 1.6112x; 1.1459x over previous
//
#include <hip/hip_runtime.h>
#include <math.h>

// HPSS fused, fp16 LDS, 32(f) x 64(t) tiles, register-fed slides.
// S (2,1,1025,2048) fp32. harm = median_31 along T (zero pad), perc = along F.
// outH = S*h^2/(h^2+p^2), outP = S*p^2/(h^2+p^2)   (softmask Z cancels).
//
// Round-9 lesson: r6 (20 waves/CU) == r7 (32 waves/CU) == 38.4us kills the
// occupancy/cohort theories; VALUBusy ~44-51% with per-slide dependent
// ds_read_u16 pairs (~120cy each, ~16 stall events/chunk) is the bottleneck.
// This version: preload the whole feed strip r[0..37] per chunk (phase H via
// 19 ds_read_b32 pairs; phase P via 38 independent scalar reads + 8 hl
// prefetch) -> slides are PURE REGISTER, ~2 waitcnt events per chunk.
// sv in phase P is r[s+15] (free). Config = proven r7: 32x64 tile, RW=8,
// grid 2112, LDS 16.4KB.
// Slide = delete+insert at O(1) dependency depth:
//   D[i] = (w[i] < x_old) ? w[i] : w[i+1]; w'[i] = med3(D[i-1], x_new, D[i]).

#define DIM_T 2048
#define DIM_F 1025
#define HALF 15
#define FT 32            // output f-rows per tile
#define TT 64            // output t-cols per tile
#define RW 8             // outputs per thread along the sliding axis
#define TROWS (FT + 30)  // 62 staged rows
#define TCOLS (TT + 30)  // 94 staged cols
#define TSTR 98          // halves; 49 dwords (odd) -> conflict-free strided
#define HSTR 66          // halves; 33 dwords (odd)
#define FEED (RW + 30)   // 38 feed values per chunk

typedef _Float16 h16;
typedef _Float16 h16x2 __attribute__((ext_vector_type(2)));

__device__ __forceinline__ h16 hmin(h16 a, h16 b) { return a < b ? a : b; }
__device__ __forceinline__ h16 hmax(h16 a, h16 b) { return a > b ? a : b; }
__device__ __forceinline__ h16 hmed3(h16 a, h16 b, h16 c) {
#if __has_builtin(__builtin_amdgcn_fmed3h)
    return __builtin_amdgcn_fmed3h(a, b, c);
#else
    return hmax(hmin(a, b), hmin(hmax(a, b), c));
#endif
}

__device__ __forceinline__ void ce(h16& a, h16& b) {
    const h16 mn = hmin(a, b);
    b = hmax(a, b);
    a = mn;
}

__device__ __forceinline__ void sort32(h16 (&a)[32]) {
#pragma unroll
    for (int p = 1; p < 32; p <<= 1) {
#pragma unroll
        for (int k = p; k >= 1; k >>= 1) {
#pragma unroll
            for (int j = k & (p - 1); j + k < 32; j += 2 * k) {
#pragma unroll
                for (int i = 0; i < k; ++i) {
                    if (i + j + k < 32) {
                        if ((i + j) / (2 * p) == (i + j + k) / (2 * p)) {
                            ce(a[i + j], a[i + j + k]);
                        }
                    }
                }
            }
        }
    }
}

// sorted-window slide: remove x_old (present in w[0..30]), insert x_new.
// w[31] must be +INF and is preserved. 31 indep (cmp+sel) + 31 indep med3.
__device__ __forceinline__ void slide(h16 (&w)[32], h16 x_old, h16 x_new) {
    h16 dprev = (w[0] < x_old) ? w[0] : w[1];
    h16 rprev = hmin(x_new, dprev);
#pragma unroll
    for (int i = 1; i < 31; ++i) {
        const h16 di = (w[i] < x_old) ? w[i] : w[i + 1];
        const h16 ri = hmed3(dprev, x_new, di);
        w[i - 1] = rprev;
        dprev = di;
        rprev = ri;
    }
    w[30] = rprev;
}

__global__ __launch_bounds__(256, 6) void hpss_fused(const float* __restrict__ S,
                                                     float* __restrict__ outH,
                                                     float* __restrict__ outP) {
    __shared__ h16 tile[TROWS * TSTR];  // 12152 B
    __shared__ h16 hl[FT * HSTR];       //  4224 B

    const int tid = threadIdx.x;
    const int t0  = blockIdx.x * TT;
    const int f0  = blockIdx.y * FT;
    const int b   = blockIdx.z;
    const float* __restrict__ Sb = S + (size_t)b * DIM_F * DIM_T;

    // ---- stage 62x94 tile as fp16, coalesced (consecutive tid -> t) ----
    const bool interior = (blockIdx.x != 0) & (blockIdx.x != gridDim.x - 1) &
                          (f0 >= HALF) & (f0 + FT + HALF <= DIM_F);
    if (interior) {
#pragma unroll
        for (int it = 0; it < (TROWS * TCOLS + 255) / 256; ++it) {  // 23 iters
            const int li = it * 256 + tid;
            if (li < TROWS * TCOLS) {
                const int row = li / TCOLS;
                const int pos = li - row * TCOLS;
                tile[row * TSTR + pos] =
                    (h16)Sb[(size_t)(f0 - HALF + row) * DIM_T + (t0 - HALF + pos)];
            }
        }
    } else {
#pragma unroll
        for (int it = 0; it < (TROWS * TCOLS + 255) / 256; ++it) {
            const int li = it * 256 + tid;
            if (li < TROWS * TCOLS) {
                const int row = li / TCOLS;
                const int pos = li - row * TCOLS;
                const int f = f0 - HALF + row;
                const int t = t0 - HALF + pos;
                float v = 0.0f;
                if ((unsigned)f < (unsigned)DIM_F && (unsigned)t < (unsigned)DIM_T)
                    v = Sb[(size_t)f * DIM_T + t];
                tile[row * TSTR + pos] = (h16)v;
            }
        }
    }
    __syncthreads();

    // ---- phase H: harmonic medians (slide along t) -> hl[f][t] ----
    {
        const int fl = tid & 31;          // output f row 0..31
        const int tb = (tid >> 5) * RW;   // t chunk base 0..56 (even)
        const h16* lr = tile + (fl + HALF) * TSTR;  // row base: even halves

        // feed strip r[0..37] via 19 dword-aligned pair loads (independent)
        h16 r[FEED];
        const h16x2* lrp = (const h16x2*)(lr + tb);
#pragma unroll
        for (int j = 0; j < FEED / 2; ++j) {
            const h16x2 p = lrp[j];
            r[2 * j]     = p[0];
            r[2 * j + 1] = p[1];
        }

        h16 w[32];
        w[31] = (h16)INFINITY;
#pragma unroll
        for (int d = 0; d < 31; ++d) w[d] = r[d];
        sort32(w);
#pragma unroll
        for (int s = 0; s < RW; ++s) {
            hl[fl * HSTR + tb + s] = w[15];
            if (s < RW - 1) slide(w, r[s], r[s + 31]);   // pure-register slide
        }
    }
    __syncthreads();

    // ---- phase P: percussive medians (slide along f) + combine + store ----
    {
        const int lane = tid & 63;        // t within tile
        const int fb   = (tid >> 6) * RW; // f chunk base 0,8,16,24
        const int t    = t0 + lane;

        // feed strip: 38 independent strided reads, issued back-to-back
        h16 r[FEED];
#pragma unroll
        for (int d = 0; d < FEED; ++d) r[d] = tile[(fb + d) * TSTR + HALF + lane];
        // harm values for this chunk (written by phase H pre-barrier)
        h16 hp[RW];
#pragma unroll
        for (int s = 0; s < RW; ++s) hp[s] = hl[(fb + s) * HSTR + lane];

        h16 w[32];
        w[31] = (h16)INFINITY;
#pragma unroll
        for (int d = 0; d < 31; ++d) w[d] = r[d];
        sort32(w);
#pragma unroll
        for (int s = 0; s < RW; ++s) {
            const int f = f0 + fb + s;
            if (f < DIM_F) {
                const float perc = (float)w[15];
                const float harm = (float)hp[s];
                const float sv   = (float)r[s + 15];   // center element, free
                const float h2 = harm * harm;
                const float p2 = perc * perc;
                const float inv = __builtin_amdgcn_rcpf(h2 + p2);  // 0 -> INF; (sv*0)*INF=NaN matches ref 0/0
                const size_t oi = ((size_t)b * DIM_F + f) * DIM_T + t;
                outH[oi] = sv * h2 * inv;
                outP[oi] = sv * p2 * inv;
            }
            if (s < RW - 1) slide(w, r[s], r[s + 31]);   // pure-register slide
        }
    }
}

extern "C" void kernel_launch(void* const* d_in, const int* in_sizes, int n_in,
                              void* d_out, int out_size, void* d_ws, size_t ws_size,
                              hipStream_t stream) {
    const float* S = (const float*)d_in[0];
    float* outH = (float*)d_out;
    float* outP = outH + (size_t)2 * DIM_F * DIM_T;

    dim3 grid(DIM_T / TT, (DIM_F + FT - 1) / FT, 2);  // 32 x 33 x 2 = 2112
    hpss_fused<<<grid, 256, 0, stream>>>(S, outH, outP);
}

// Round 11
// 37.989 us; speedup vs baseline: 1.8542x; 1.1508x over previous
//
#include <hip/hip_runtime.h>
#include <math.h>

// HPSS fused, fp32 everywhere, register-fed slides. S (2,1,1025,2048) fp32.
// harm = median_31 along T (zero pad), perc = median_31 along F.
// outH = S*h^2/(h^2+p^2), outP = S*p^2/(h^2+p^2)   (softmask Z cancels).
//
// Round-10 lesson: fp16 window math was a VALU PESSIMIZATION — the h16
// min/max fell back to cmp+cndmask (3 ops/CE vs 2) and 2-per-VGPR packing
// added extract/insert on every access; dur*VALUBusy rose 67%. This version
// keeps r10's register-fed slide structure (the part that worked: stalls
// 44%->65% busy) but in plain f32: v_min_f32/v_max_f32/v_med3_f32, one
// element per VGPR, no conversions.
//   - 32(f) x 64(t) tile, RW=8, grid 32x33x2 = 2112.
//   - Per chunk: preload feed strip r[0..37] (phase H: contiguous row reads;
//     phase P: 38 strided reads, all independent, one waitcnt) -> slide loop
//     touches ZERO LDS. sv = r[s+15] free in phase P.
//   - LDS strides odd in dwords (95 / 65) -> conflict-free both phases.
//   - __launch_bounds__(256,4): 128-VGPR cap for ~95 live (w32+r38+hp8+addr).
// Slide = delete+insert at O(1) dependency depth:
//   D[i] = (w[i] < x_old) ? w[i] : w[i+1]; w'[i] = med3(D[i-1], x_new, D[i]).

#define DIM_T 2048
#define DIM_F 1025
#define HALF 15
#define FT 32            // output f-rows per tile
#define TT 64            // output t-cols per tile
#define RW 8             // outputs per thread along the sliding axis
#define TROWS (FT + 30)  // 62 staged rows
#define TCOLS (TT + 30)  // 94 staged cols
#define TSTR 95          // dwords, odd -> conflict-free strided access
#define HSTR 65          // dwords, odd
#define FEED (RW + 30)   // 38 feed values per chunk

__device__ __forceinline__ void ce(float& a, float& b) {
    const float mn = fminf(a, b);
    b = fmaxf(a, b);
    a = mn;
}

__device__ __forceinline__ void sort32(float (&a)[32]) {
#pragma unroll
    for (int p = 1; p < 32; p <<= 1) {
#pragma unroll
        for (int k = p; k >= 1; k >>= 1) {
#pragma unroll
            for (int j = k & (p - 1); j + k < 32; j += 2 * k) {
#pragma unroll
                for (int i = 0; i < k; ++i) {
                    if (i + j + k < 32) {
                        if ((i + j) / (2 * p) == (i + j + k) / (2 * p)) {
                            ce(a[i + j], a[i + j + k]);
                        }
                    }
                }
            }
        }
    }
}

// sorted-window slide: remove x_old (present in w[0..30]), insert x_new.
// w[31] must be +INF and is preserved. 31 indep (cmp+sel) + 31 indep med3.
__device__ __forceinline__ void slide(float (&w)[32], float x_old, float x_new) {
    float dprev = (w[0] < x_old) ? w[0] : w[1];
    float rprev = fminf(x_new, dprev);
#pragma unroll
    for (int i = 1; i < 31; ++i) {
        const float di = (w[i] < x_old) ? w[i] : w[i + 1];
        const float ri = __builtin_amdgcn_fmed3f(dprev, x_new, di);
        w[i - 1] = rprev;
        dprev = di;
        rprev = ri;
    }
    w[30] = rprev;
}

__global__ __launch_bounds__(256, 4) void hpss_fused(const float* __restrict__ S,
                                                     float* __restrict__ outH,
                                                     float* __restrict__ outP) {
    __shared__ float tile[TROWS * TSTR];  // 23560 B
    __shared__ float hl[FT * HSTR];       //  8320 B

    const int tid = threadIdx.x;
    const int t0  = blockIdx.x * TT;
    const int f0  = blockIdx.y * FT;
    const int b   = blockIdx.z;
    const float* __restrict__ Sb = S + (size_t)b * DIM_F * DIM_T;

    // ---- stage 62x94 tile, coalesced (consecutive tid -> consecutive t) ----
    const bool interior = (blockIdx.x != 0) & (blockIdx.x != gridDim.x - 1) &
                          (f0 >= HALF) & (f0 + FT + HALF <= DIM_F);
    if (interior) {
#pragma unroll
        for (int it = 0; it < (TROWS * TCOLS + 255) / 256; ++it) {  // 23 iters
            const int li = it * 256 + tid;
            if (li < TROWS * TCOLS) {
                const int row = li / TCOLS;
                const int pos = li - row * TCOLS;
                tile[row * TSTR + pos] =
                    Sb[(size_t)(f0 - HALF + row) * DIM_T + (t0 - HALF + pos)];
            }
        }
    } else {
#pragma unroll
        for (int it = 0; it < (TROWS * TCOLS + 255) / 256; ++it) {
            const int li = it * 256 + tid;
            if (li < TROWS * TCOLS) {
                const int row = li / TCOLS;
                const int pos = li - row * TCOLS;
                const int f = f0 - HALF + row;
                const int t = t0 - HALF + pos;
                float v = 0.0f;
                if ((unsigned)f < (unsigned)DIM_F && (unsigned)t < (unsigned)DIM_T)
                    v = Sb[(size_t)f * DIM_T + t];
                tile[row * TSTR + pos] = v;
            }
        }
    }
    __syncthreads();

    // ---- phase H: harmonic medians (slide along t) -> hl[f][t] ----
    {
        const int fl = tid & 31;          // output f row 0..31
        const int tb = (tid >> 5) * RW;   // t chunk base 0..56
        const float* lr = tile + (fl + HALF) * TSTR + tb;

        // feed strip r[0..37]: contiguous, independent, one waitcnt
        float r[FEED];
#pragma unroll
        for (int d = 0; d < FEED; ++d) r[d] = lr[d];

        float w[32];
        w[31] = INFINITY;
#pragma unroll
        for (int d = 0; d < 31; ++d) w[d] = r[d];
        sort32(w);
#pragma unroll
        for (int s = 0; s < RW; ++s) {
            hl[fl * HSTR + tb + s] = w[15];
            if (s < RW - 1) slide(w, r[s], r[s + 31]);   // pure-register slide
        }
    }
    __syncthreads();

    // ---- phase P: percussive medians (slide along f) + combine + store ----
    {
        const int lane = tid & 63;        // t within tile
        const int fb   = (tid >> 6) * RW; // f chunk base 0,8,16,24
        const int t    = t0 + lane;

        // feed strip: 38 independent strided reads, issued back-to-back
        float r[FEED];
#pragma unroll
        for (int d = 0; d < FEED; ++d) r[d] = tile[(fb + d) * TSTR + HALF + lane];
        // harm values for this chunk (written by phase H pre-barrier)
        float hp[RW];
#pragma unroll
        for (int s = 0; s < RW; ++s) hp[s] = hl[(fb + s) * HSTR + lane];

        float w[32];
        w[31] = INFINITY;
#pragma unroll
        for (int d = 0; d < 31; ++d) w[d] = r[d];
        sort32(w);
#pragma unroll
        for (int s = 0; s < RW; ++s) {
            const int f = f0 + fb + s;
            if (f < DIM_F) {
                const float perc = w[15];
                const float harm = hp[s];
                const float sv   = r[s + 15];   // center element, free
                const float h2 = harm * harm;
                const float p2 = perc * perc;
                const float inv = __builtin_amdgcn_rcpf(h2 + p2);  // 0 -> INF; (sv*0)*INF=NaN matches ref 0/0
                const size_t oi = ((size_t)b * DIM_F + f) * DIM_T + t;
                outH[oi] = sv * h2 * inv;
                outP[oi] = sv * p2 * inv;
            }
            if (s < RW - 1) slide(w, r[s], r[s + 31]);   // pure-register slide
        }
    }
}

extern "C" void kernel_launch(void* const* d_in, const int* in_sizes, int n_in,
                              void* d_out, int out_size, void* d_ws, size_t ws_size,
                              hipStream_t stream) {
    const float* S = (const float*)d_in[0];
    float* outH = (float*)d_out;
    float* outP = outH + (size_t)2 * DIM_F * DIM_T;

    dim3 grid(DIM_T / TT, (DIM_F + FT - 1) / FT, 2);  // 32 x 33 x 2 = 2112
    hpss_fused<<<grid, 256, 0, stream>>>(S, outH, outP);
}